// Round 8
// baseline (155.646 us; speedup 1.0000x reference)
//
#include <hip/hip_runtime.h>
#include <hip/hip_bf16.h>
#include <math.h>

#define B_DIM 8
#define C_DIM 32
#define N_DIM 4096
#define KSL 512          // k per wave; 8 waves cover 4096
#define NCH (KSL / 32)   // 16 chunks per wave
#define BLOCAL 4         // batches per block (blockIdx.y selects group)

typedef short bf16x8 __attribute__((ext_vector_type(8)));   // 8 bf16 = 4 VGPRs
typedef float f32x4 __attribute__((ext_vector_type(4)));
typedef unsigned int uint4v __attribute__((ext_vector_type(4)));

__device__ __forceinline__ ushort f2bf_rne(float f) {
  unsigned u = __float_as_uint(f);
  u += 0x7FFF + ((u >> 16) & 1);
  return (ushort)(u >> 16);
}

// Kernel 1: cadjs[b,n] = mean_c x[b,c,n] * log2(e)  (pre-scaled for exp2);
// feabT tiled bf16: feabT[((b*128 + n/32)*32 + c)*32 + n%32]
__global__ __launch_bounds__(256) void prep_kernel(const float* __restrict__ x,
                                                   float* __restrict__ cadjs,
                                                   ushort* __restrict__ feabT) {
  int idx = blockIdx.x * 256 + threadIdx.x;   // 0 .. B*N-1
  int b = idx >> 12;
  int n = idx & (N_DIM - 1);
  const float* p = x + (size_t)b * C_DIM * N_DIM + n;
  ushort* q = feabT + ((size_t)(b * (N_DIM / 32) + (n >> 5)) * C_DIM) * 32 + (n & 31);
  float s = 0.f;
#pragma unroll
  for (int c = 0; c < C_DIM; ++c) {
    float v = p[(size_t)c * N_DIM];
    s += v;
    q[(size_t)c * 32] = f2bf_rne(v);
  }
  cadjs[idx] = s * (1.44269504f / C_DIM);   // scaled by log2(e): |a-b|*s = |as-bs|
}

// Kernel 2 (fused): block = 8 waves; wave wv = K-slice [wv*512, ...+512),
// BLOCAL=4 batches (blockIdx.y picks group), 16 cols. Grid 512 -> 2 blocks/CU
// (the r7 fix: grid 256 capped the chip at 1 block/CU = 2 waves/SIMD).
// Pair-blocks (x,0)/(x,1) share an XCD (ids differ by 256 = 0 mod 8) -> adj
// stripe fetched ~once per XCD L2. Batch loop software-pipelined depth-2;
// adj double-buffered, staged mid-chunk. LDS cross-wave reduce + para*relu.
__global__ __launch_bounds__(512, 4) void gcn_fused(
    const ushort* __restrict__ feabT, const float* __restrict__ adj,
    const float* __restrict__ cadjs, const float* __restrict__ para,
    float* __restrict__ out) {
  __shared__ float red[8][BLOCAL * 512];   // 64 KB

  const int tid = threadIdx.x;
  const int lane = tid & 63;
  const int wv = tid >> 6;          // 0..7 = K-slice
  const int quad = lane >> 4;
  const int l15 = lane & 15;
  const int colgrp = blockIdx.x;    // 0..255
  const int b0 = blockIdx.y * BLOCAL;
  const int col = colgrp * 16 + l15;
  const int ksbase = wv * KSL;

  float cm[BLOCAL];
#pragma unroll
  for (int b = 0; b < BLOCAL; ++b) cm[b] = cadjs[(b0 + b) * N_DIM + col];

  f32x4 acc[BLOCAL][2];
#pragma unroll
  for (int b = 0; b < BLOCAL; ++b) {
    acc[b][0] = (f32x4){0.f, 0.f, 0.f, 0.f};
    acc[b][1] = (f32x4){0.f, 0.f, 0.f, 0.f};
  }

  float a2[2][8];          // 2*adj, double-buffered across chunks
  bf16x8 fa0[2], fa1[2];   // fea fragments, double-buffered across batches
  float ckv[2][8];         // cadjs k-values, double-buffered across batches

#define ADJ_STAGE(ch, s)                                                      \
  {                                                                           \
    const int kr = ksbase + (ch) * 32 + quad * 8;                             \
    _Pragma("unroll")                                                         \
    for (int j = 0; j < 8; ++j)                                               \
      a2[s][j] = 2.0f * adj[(size_t)(kr + j) * N_DIM + col];                  \
  }

#define LOAD_FEA(ch, b_, s)                                                   \
  {                                                                           \
    const int kb2 = ksbase + (ch) * 32;                                       \
    const ushort* tile =                                                      \
        feabT + (size_t)((b0 + (b_)) * (N_DIM / 32) + (kb2 >> 5)) * (C_DIM * 32); \
    fa0[s] = *(const bf16x8*)(tile + l15 * 32 + quad * 8);                    \
    fa1[s] = *(const bf16x8*)(tile + (16 + l15) * 32 + quad * 8);             \
    *(f32x4*)&ckv[s][0] =                                                     \
        *(const f32x4*)(cadjs + (size_t)(b0 + (b_)) * N_DIM + kb2 + quad * 8); \
    *(f32x4*)&ckv[s][4] =                                                     \
        *(const f32x4*)(cadjs + (size_t)(b0 + (b_)) * N_DIM + kb2 + quad * 8 + 4); \
  }

  ADJ_STAGE(0, 0)
  LOAD_FEA(0, 0, 0)

#pragma unroll 2
  for (int ch = 0; ch < NCH; ++ch) {
    const int s = ch & 1;

#pragma unroll
    for (int b = 0; b < BLOCAL; ++b) {
      const int sb = b & 1;
      // prefetch next batch (or batch 0 of next chunk)
      if (b < BLOCAL - 1) {
        LOAD_FEA(ch, b + 1, sb ^ 1)
      } else if (ch + 1 < NCH) {
        LOAD_FEA(ch + 1, 0, 0)
      }
      // adj prefetch mid-chunk: nearest later fea-wait is ~1 batch away
      if (b == 1 && ch + 1 < NCH) ADJ_STAGE(ch + 1, s ^ 1)

      // w = 2*adj / (1 + exp2(|ck' - cm'|)), inputs pre-scaled by log2(e)
      uint4v wfu;
#pragma unroll
      for (int p = 0; p < 4; ++p) {
        float d0 = ckv[sb][2 * p] - cm[b];
        float e0 = __builtin_amdgcn_exp2f(fabsf(d0));
        float w0 = a2[s][2 * p] * __builtin_amdgcn_rcpf(1.0f + e0);
        float d1 = ckv[sb][2 * p + 1] - cm[b];
        float e1 = __builtin_amdgcn_exp2f(fabsf(d1));
        float w1 = a2[s][2 * p + 1] * __builtin_amdgcn_rcpf(1.0f + e1);
        // truncating bf16x2 pack: bytes [w0.b2, w0.b3, w1.b2, w1.b3]
        wfu[p] = __builtin_amdgcn_perm(__float_as_uint(w1), __float_as_uint(w0),
                                       0x07060302u);
      }
      const bf16x8 wf = __builtin_bit_cast(bf16x8, wfu);

      acc[b][0] = __builtin_amdgcn_mfma_f32_16x16x32_bf16(fa0[sb], wf, acc[b][0], 0, 0, 0);
      acc[b][1] = __builtin_amdgcn_mfma_f32_16x16x32_bf16(fa1[sb], wf, acc[b][1], 0, 0, 0);
    }
  }

  // stash all 4 batches, single pass (D layout: col=l15, row=quad*4+r)
#pragma unroll
  for (int bl = 0; bl < BLOCAL; ++bl)
#pragma unroll
    for (int h = 0; h < 2; ++h)
#pragma unroll
      for (int r = 0; r < 4; ++r)
        red[wv][bl * 512 + (h * 16 + quad * 4 + r) * 16 + l15] = acc[bl][h][r];
  __syncthreads();

  // cross-wave reduce + epilogue: 4 outputs per thread
  const float pv = para[(size_t)(tid >> 4) * N_DIM + colgrp * 16 + (tid & 15)];
#pragma unroll
  for (int q = 0; q < BLOCAL; ++q) {
    float ssum = 0.f;
#pragma unroll
    for (int w = 0; w < 8; ++w) ssum += red[w][q * 512 + tid];
    const int c = tid >> 4;
    const int ocol = colgrp * 16 + (tid & 15);
    out[((size_t)((b0 + q) * C_DIM + c)) * N_DIM + ocol] = fmaxf(ssum * pv, 0.f);
  }
}

extern "C" void kernel_launch(void* const* d_in, const int* in_sizes, int n_in,
                              void* d_out, int out_size, void* d_ws, size_t ws_size,
                              hipStream_t stream) {
  const float* x = (const float*)d_in[0];     // [8,32,64,64]
  const float* para = (const float*)d_in[1];  // [1,32,64,64]
  const float* adj = (const float*)d_in[2];   // [4096,4096]
  float* out = (float*)d_out;

  // ws: cadjs (128 KB) | feabT (2 MB)  -- total 2.25 MB
  float* cadjs = (float*)d_ws;
  ushort* feabT = (ushort*)((char*)d_ws + (size_t)B_DIM * N_DIM * 4);

  prep_kernel<<<dim3(B_DIM * N_DIM / 256), dim3(256), 0, stream>>>(x, cadjs, feabT);
  gcn_fused<<<dim3(N_DIM / 16, B_DIM / BLOCAL), dim3(512), 0, stream>>>(feabT, adj, cadjs, para, out);
}

// Round 9
// 153.582 us; speedup vs baseline: 1.0134x; 1.0134x over previous
//
#include <hip/hip_runtime.h>
#include <hip/hip_bf16.h>
#include <math.h>

#define B_DIM 8
#define C_DIM 32
#define N_DIM 4096
#define KSL 512          // k per wave; 8 waves cover 4096
#define NCH (KSL / 32)   // 16 chunks per wave

typedef short bf16x8 __attribute__((ext_vector_type(8)));   // 8 bf16 = 4 VGPRs
typedef float f32x4 __attribute__((ext_vector_type(4)));
typedef unsigned int uint4v __attribute__((ext_vector_type(4)));
typedef unsigned short ushort8 __attribute__((ext_vector_type(8)));

__device__ __forceinline__ ushort f2bf_rne(float f) {
  unsigned u = __float_as_uint(f);
  u += 0x7FFF + ((u >> 16) & 1);
  return (ushort)(u >> 16);
}

// Prep A: cadjs[b,n] = mean_c x[b,c,n] * log2(e)   (pre-scaled for exp2)
__global__ __launch_bounds__(256) void prep_cadj(const float* __restrict__ x,
                                                 float* __restrict__ cadjs) {
  int idx = blockIdx.x * 256 + threadIdx.x;   // 0 .. B*N-1
  int b = idx >> 12;
  int n = idx & (N_DIM - 1);
  const float* p = x + (size_t)b * C_DIM * N_DIM + n;
  float s = 0.f;
#pragma unroll
  for (int c = 0; c < C_DIM; ++c) s += p[(size_t)c * N_DIM];
  cadjs[idx] = s * (1.44269504f / C_DIM);
}

// Prep B: feabT tiled bf16: feabT[((b*128 + n/32)*32 + c)*32 + n%32]
// One thread per (b,c,16-n-group): 64-B coalesced read, 32-B contiguous write.
__global__ __launch_bounds__(256) void prep_feab(const float* __restrict__ x,
                                                 ushort* __restrict__ feabT) {
  int idx = blockIdx.x * 256 + threadIdx.x;   // 0 .. 8*32*256-1
  int g = idx & 255;           // n-group of 16
  int c = (idx >> 8) & 31;
  int b = idx >> 13;
  int n0 = g * 16;
  const float* p = x + ((size_t)(b * C_DIM + c)) * N_DIM + n0;
  ushort* q = feabT + ((size_t)(b * (N_DIM / 32) + (n0 >> 5)) * C_DIM + c) * 32 + (n0 & 31);
  ushort8 v0, v1;
#pragma unroll
  for (int j = 0; j < 8; ++j) v0[j] = f2bf_rne(p[j]);
#pragma unroll
  for (int j = 0; j < 8; ++j) v1[j] = f2bf_rne(p[8 + j]);
  *(ushort8*)q = v0;
  *(ushort8*)(q + 8) = v1;
}

// Fused kernel: block = 8 waves; wave wv = K-slice [wv*512, ...+512), all 8
// batches, 16 cols. Depth-4 fea/ckv rotation: batch b consumes slot b&3 issued
// ~2.3 batch bodies earlier (~500 VALU cyc > L2/L3 latency). adj staged at
// b==0 for ch+1 (~8 bodies, covers HBM latency; FIFO wait subsumed by fea
// waits). LDS cross-wave reduce + fused para*relu epilogue.
__global__ __launch_bounds__(512, 2) void gcn_fused(
    const ushort* __restrict__ feabT, const float* __restrict__ adj,
    const float* __restrict__ cadjs, const float* __restrict__ para,
    float* __restrict__ out) {
  __shared__ float red[8][2048];   // 64 KB

  const int tid = threadIdx.x;
  const int lane = tid & 63;
  const int wv = tid >> 6;          // 0..7 = K-slice
  const int quad = lane >> 4;
  const int l15 = lane & 15;
  const int colgrp = blockIdx.x;    // 0..255
  const int col = colgrp * 16 + l15;
  const int ksbase = wv * KSL;

  float cm[B_DIM];
#pragma unroll
  for (int b = 0; b < B_DIM; ++b) cm[b] = cadjs[b * N_DIM + col];

  f32x4 acc[B_DIM][2];
#pragma unroll
  for (int b = 0; b < B_DIM; ++b) {
    acc[b][0] = (f32x4){0.f, 0.f, 0.f, 0.f};
    acc[b][1] = (f32x4){0.f, 0.f, 0.f, 0.f};
  }

  float a2[2][8];          // 2*adj, double-buffered across chunks
  bf16x8 fa0[4], fa1[4];   // fea fragments, depth-4 rotation
  float ckv[4][8];         // cadjs k-values, depth-4 rotation

#define ADJ_STAGE(ch, s)                                                      \
  {                                                                           \
    const int kr = ksbase + (ch) * 32 + quad * 8;                             \
    _Pragma("unroll")                                                         \
    for (int j = 0; j < 8; ++j)                                               \
      a2[s][j] = 2.0f * adj[(size_t)(kr + j) * N_DIM + col];                  \
  }

#define LOAD_FEA(ch, b_, s)                                                   \
  {                                                                           \
    const int kb2 = ksbase + (ch) * 32;                                       \
    const ushort* tile =                                                      \
        feabT + (size_t)((b_) * (N_DIM / 32) + (kb2 >> 5)) * (C_DIM * 32);    \
    fa0[s] = *(const bf16x8*)(tile + l15 * 32 + quad * 8);                    \
    fa1[s] = *(const bf16x8*)(tile + (16 + l15) * 32 + quad * 8);             \
    *(f32x4*)&ckv[s][0] = *(const f32x4*)(cadjs + (size_t)(b_)*N_DIM + kb2 + quad * 8); \
    *(f32x4*)&ckv[s][4] = *(const f32x4*)(cadjs + (size_t)(b_)*N_DIM + kb2 + quad * 8 + 4); \
  }

  // Prologue: adj first (so its FIFO wait is cheapest), then 3 fea slots.
  ADJ_STAGE(0, 0)
  LOAD_FEA(0, 0, 0)
  LOAD_FEA(0, 1, 1)
  LOAD_FEA(0, 2, 2)

  for (int ch = 0; ch < NCH; ++ch) {
    const int s = ch & 1;

#pragma unroll
    for (int b = 0; b < B_DIM; ++b) {
      const int sb = b & 3;
      // deep prefetch: (ch, b+3) or (ch+1, b-5); slot (b+3)&3
      if (b < 5) {
        LOAD_FEA(ch, b + 3, (b + 3) & 3)
      } else if (ch + 1 < NCH) {
        LOAD_FEA(ch + 1, b - 5, (b + 3) & 3)
      }
      // adj for next chunk staged at the top: ~8 batch bodies of distance
      if (b == 0 && ch + 1 < NCH) ADJ_STAGE(ch + 1, s ^ 1)

      // w = 2*adj / (1 + exp2(|ck' - cm'|)), inputs pre-scaled by log2(e)
      uint4v wfu;
#pragma unroll
      for (int p = 0; p < 4; ++p) {
        float d0 = ckv[sb][2 * p] - cm[b];
        float e0 = __builtin_amdgcn_exp2f(fabsf(d0));
        float w0 = a2[s][2 * p] * __builtin_amdgcn_rcpf(1.0f + e0);
        float d1 = ckv[sb][2 * p + 1] - cm[b];
        float e1 = __builtin_amdgcn_exp2f(fabsf(d1));
        float w1 = a2[s][2 * p + 1] * __builtin_amdgcn_rcpf(1.0f + e1);
        // truncating bf16x2 pack: bytes [w0.b2, w0.b3, w1.b2, w1.b3]
        wfu[p] = __builtin_amdgcn_perm(__float_as_uint(w1), __float_as_uint(w0),
                                       0x07060302u);
      }
      const bf16x8 wf = __builtin_bit_cast(bf16x8, wfu);

      acc[b][0] = __builtin_amdgcn_mfma_f32_16x16x32_bf16(fa0[sb], wf, acc[b][0], 0, 0, 0);
      acc[b][1] = __builtin_amdgcn_mfma_f32_16x16x32_bf16(fa1[sb], wf, acc[b][1], 0, 0, 0);
    }
  }

  // para value for this thread's (c, col16) slot in the reduce phase
  const float pv = para[(size_t)(tid >> 4) * N_DIM + colgrp * 16 + (tid & 15)];

  // cross-wave reduction + epilogue, 2 passes of 4 batches (LDS = 64 KB)
#pragma unroll
  for (int pass = 0; pass < 2; ++pass) {
    if (pass) __syncthreads();   // pass-0 reads done before overwrite
#pragma unroll
    for (int bl = 0; bl < 4; ++bl) {
      const int b = pass * 4 + bl;
#pragma unroll
      for (int h = 0; h < 2; ++h)
#pragma unroll
        for (int r = 0; r < 4; ++r)
          red[wv][bl * 512 + (h * 16 + quad * 4 + r) * 16 + l15] = acc[b][h][r];
    }
    __syncthreads();
#pragma unroll
    for (int q = 0; q < 4; ++q) {
      float ssum = 0.f;
#pragma unroll
      for (int w = 0; w < 8; ++w) ssum += red[w][q * 512 + tid];
      const int b = pass * 4 + q;
      const int c = tid >> 4;
      const int ocol = colgrp * 16 + (tid & 15);
      out[((size_t)(b * C_DIM + c)) * N_DIM + ocol] = fmaxf(ssum * pv, 0.f);
    }
  }
}

extern "C" void kernel_launch(void* const* d_in, const int* in_sizes, int n_in,
                              void* d_out, int out_size, void* d_ws, size_t ws_size,
                              hipStream_t stream) {
  const float* x = (const float*)d_in[0];     // [8,32,64,64]
  const float* para = (const float*)d_in[1];  // [1,32,64,64]
  const float* adj = (const float*)d_in[2];   // [4096,4096]
  float* out = (float*)d_out;

  // ws: cadjs (128 KB) | feabT (2 MB)  -- total 2.25 MB
  float* cadjs = (float*)d_ws;
  ushort* feabT = (ushort*)((char*)d_ws + (size_t)B_DIM * N_DIM * 4);

  prep_cadj<<<dim3(B_DIM * N_DIM / 256), dim3(256), 0, stream>>>(x, cadjs);
  prep_feab<<<dim3(B_DIM * C_DIM * (N_DIM / 16) / 256), dim3(256), 0, stream>>>(x, feabT);
  gcn_fused<<<dim3(N_DIM / 16), dim3(512), 0, stream>>>(feabT, adj, cadjs, para, out);
}